// Round 2
// 399.261 us; speedup vs baseline: 1.2125x; 1.2125x over previous
//
#include <hip/hip_runtime.h>
#include <hip/hip_bf16.h>

#define NB 16
#define NL 2048
#define ND 128
#define QSCALE 0.08838834764831845f
// scale with log2(e) folded in: exp(s) == exp2(s * log2e); fold into Q pre-scale
#define QSCALE2 (0.08838834764831845f * 1.4426950408889634f)

using short8 = __attribute__((ext_vector_type(8))) short;
using f32x4  = __attribute__((ext_vector_type(4))) float;

// raw hardware exp2: v_exp_f32 computes 2^x
__device__ __forceinline__ float hw_exp2(float x) {
  return __builtin_amdgcn_exp2f(x);
}

// fp32 -> bf16 bits, round-to-nearest-even
__device__ __forceinline__ unsigned short bfr(float f) {
  unsigned u = __float_as_uint(f);
  unsigned r = u + 0x7FFFu + ((u >> 16) & 1u);
  return (unsigned short)(r >> 16);
}
__device__ __forceinline__ float bf2f(unsigned short h) {
  return __uint_as_float(((unsigned)h) << 16);
}
__device__ __forceinline__ unsigned pk(float a, float b) {
  return (unsigned)bfr(a) | ((unsigned)bfr(b) << 16);
}

// async global->LDS, 16B per lane. LDS dest is wave-uniform base + lane*16.
typedef const __attribute__((address_space(1))) unsigned int* gas1_t;
typedef __attribute__((address_space(3))) unsigned int* las3_t;
__device__ __forceinline__ void async_lds16(const unsigned short* g, unsigned short* l) {
  __builtin_amdgcn_global_load_lds((gas1_t)g, (las3_t)l, 16, 0, 0);
}

// Read a 16B fragment from a LINEAR [128][128] ushort LDS tile with the
// T2 chunk swizzle applied (chunk ^= row&7). Bank-balanced for b128 reads.
__device__ __forceinline__ short8 swz_frag(const unsigned short* base, int row, int chunk) {
  return *(const short8*)(base + row * 128 + (((chunk ^ (row & 7)) << 3)));
}

// Workspace layout (bytes):
//   Kb  bf16 [B][L][D]  @ 0          (8388608)
//   Vt  bf16 [B][D][L]  @ 8388608    (8388608)
//   linv f32 [B][L]     @ 16777216   (131072)
#define WS_KB 0
#define WS_VT 8388608
#define WS_LINV 16777216
#define WS_NEED 16908288

// ---------------- prep: K f32 -> bf16, coalesced ----------------
__global__ __launch_bounds__(256)
void prep_k(const float* __restrict__ kg, unsigned short* __restrict__ Kb) {
  size_t base = ((size_t)blockIdx.x * 256 + threadIdx.x) * 4;
  float4 x = *(const float4*)(kg + base);
  ushort4 o;
  o.x = bfr(x.x); o.y = bfr(x.y); o.z = bfr(x.z); o.w = bfr(x.w);
  *(ushort4*)(Kb + base) = o;
}

// ---------------- prep: V f32 -> bf16 transposed [B][D][L], LDS-tiled ----------------
__global__ __launch_bounds__(256)
void prep_vt(const float* __restrict__ vg, unsigned short* __restrict__ Vt) {
  __shared__ float T[32][129];
  const int b = blockIdx.y, j0 = blockIdx.x * 32, tid = threadIdx.x;
  const float* vb = vg + ((size_t)b * NL + j0) * ND;
#pragma unroll
  for (int r = 0; r < 4; ++r) {
    int f4 = tid + r * 256;
    int j  = f4 >> 5;
    int c4 = f4 & 31;
    float4 x = *(const float4*)(vb + (size_t)j * ND + c4 * 4);
    T[j][c4 * 4 + 0] = x.x; T[j][c4 * 4 + 1] = x.y;
    T[j][c4 * 4 + 2] = x.z; T[j][c4 * 4 + 3] = x.w;
  }
  __syncthreads();
  const int d = tid >> 1, h = tid & 1;
  unsigned short* orow = Vt + ((size_t)b * ND + d) * NL + j0 + h * 16;
#pragma unroll
  for (int g = 0; g < 4; ++g) {
    ushort4 o;
    o.x = bfr(T[h * 16 + g * 4 + 0][d]);
    o.y = bfr(T[h * 16 + g * 4 + 1][d]);
    o.z = bfr(T[h * 16 + g * 4 + 2][d]);
    o.w = bfr(T[h * 16 + g * 4 + 3][d]);
    *(ushort4*)(orow + g * 4) = o;
  }
}

// Build split-precision Q fragments for 16 rows (per-lane: row l16, k = quad*8+t).
// Same register contents serve as A-frag (m=l16) or B-frag (n=l16).
__device__ __forceinline__ void load_q_frags(const float* qrow, int quad,
                                             short8* qh, short8* ql, float scale) {
#pragma unroll
  for (int kk = 0; kk < 4; ++kk) {
    const float* p = qrow + kk * 32 + quad * 8;
    float4 x = *(const float4*)(p);
    float4 y = *(const float4*)(p + 4);
    float e[8] = {x.x, x.y, x.z, x.w, y.x, y.y, y.z, y.w};
    short8 th, tl;
#pragma unroll
    for (int t = 0; t < 8; ++t) {
      float qs = e[t] * scale;
      unsigned short h = bfr(qs);
      th[t] = (short)h;
      tl[t] = (short)bfr(qs - bf2f(h));
    }
    qh[kk] = th;
    ql[kk] = tl;
  }
}

// ---------------- kernel A: ctx + linv ----------------
// grid (32 i-tiles, 16 b), block 256 = 4 waves x 16 q-rows.
// SWAPPED QK mfma (A=K, B=Q): D[j][i]; lane col=i (l16), rows=4 consecutive j.
// K,V tiles staged via global_load_lds into linear LDS with XOR chunk swizzle.
__global__ __launch_bounds__(256, 2)
void attn_ctx(const float* __restrict__ q, const unsigned short* __restrict__ Kb,
              const unsigned short* __restrict__ Vt,
              float* __restrict__ ctx, float* __restrict__ linv_ws) {
  __shared__ unsigned short KsL[128 * 128];   // linear, chunk-swizzled
  __shared__ unsigned short VsL[128 * 128];   // linear, chunk-swizzled
  __shared__ unsigned short Ps[4][16][36];    // per-wave P chunk [i][j], pad 4

  const int b    = blockIdx.y;
  const int i0   = blockIdx.x * 64;
  const int tid  = threadIdx.x;
  const int wave = tid >> 6;
  const int lane = tid & 63;
  const int quad = lane >> 4;
  const int l16  = lane & 15;

  const float* qrow = q + ((size_t)b * NL + i0 + wave * 16 + l16) * ND;
  short8 qh[4], ql[4];
  load_q_frags(qrow, quad, qh, ql, QSCALE2);

  f32x4 oacc[8];
#pragma unroll
  for (int i = 0; i < 8; ++i) oacc[i] = (f32x4){0.f, 0.f, 0.f, 0.f};
  float lsum = 0.f;   // lane-local: all of this lane's exp values are row i=l16

  const unsigned short* kbb = Kb + (size_t)b * NL * ND;
  const unsigned short* vtb = Vt + (size_t)b * ND * NL;

  for (int j0 = 0; j0 < NL; j0 += 128) {
    __syncthreads();
    // ---- async stage K tile (128 rows x 256B), source pre-swizzled ----
#pragma unroll
    for (int r = 0; r < 8; ++r) {
      int row = wave * 4 + r * 16 + (lane >> 4);
      int c   = lane & 15;
      async_lds16(kbb + (size_t)(j0 + row) * ND + ((c ^ (row & 7)) << 3),
                  KsL + (wave * 64 + r * 256) * 8);
    }
    // ---- async stage V^T tile (128 d-rows x 256B) ----
#pragma unroll
    for (int r = 0; r < 8; ++r) {
      int d = wave * 4 + r * 16 + (lane >> 4);
      int c = lane & 15;
      async_lds16(vtb + (size_t)d * NL + j0 + ((c ^ (d & 7)) << 3),
                  VsL + (wave * 64 + r * 256) * 8);
    }
    __syncthreads();   // compiler drains vmcnt here -> tiles resident

    // ---- 4 chunks of 32 j-rows each ----
#pragma unroll
    for (int ks = 0; ks < 4; ++ks) {
      f32x4 a0 = {0.f, 0.f, 0.f, 0.f}, a1 = {0.f, 0.f, 0.f, 0.f};
#pragma unroll
      for (int kk = 0; kk < 4; ++kk) {
        short8 k0 = swz_frag(KsL, ks * 32 + l16, kk * 4 + quad);
        short8 k1 = swz_frag(KsL, ks * 32 + 16 + l16, kk * 4 + quad);
        // swapped: A=K (m=j), B=Q (n=i)
        a0 = __builtin_amdgcn_mfma_f32_16x16x32_bf16(k0, qh[kk], a0, 0, 0, 0);
        a0 = __builtin_amdgcn_mfma_f32_16x16x32_bf16(k0, ql[kk], a0, 0, 0, 0);
        a1 = __builtin_amdgcn_mfma_f32_16x16x32_bf16(k1, qh[kk], a1, 0, 0, 0);
        a1 = __builtin_amdgcn_mfma_f32_16x16x32_bf16(k1, ql[kk], a1, 0, 0, 0);
      }
      // lane holds j = ks*32 + quad*4+r (a0) and +16 (a1), all for row i=l16
      float e0[4], e1[4];
#pragma unroll
      for (int r = 0; r < 4; ++r) {
        e0[r] = hw_exp2(a0[r]);
        e1[r] = hw_exp2(a1[r]);
        lsum += e0[r] + e1[r];
      }
      uint2 w0, w1;
      w0.x = pk(e0[0], e0[1]); w0.y = pk(e0[2], e0[3]);
      w1.x = pk(e1[0], e1[1]); w1.y = pk(e1[2], e1[3]);
      *(uint2*)&Ps[wave][l16][quad * 4]      = w0;   // cols quad*4..+3
      *(uint2*)&Ps[wave][l16][16 + quad * 4] = w1;   // cols 16+quad*4..+3
      // wave-private round-trip (no barrier): A-frag P[i=l16][j=quad*8+t]
      short8 pa = *(const short8*)&Ps[wave][l16][quad * 8];
#pragma unroll
      for (int dt = 0; dt < 8; ++dt) {
        short8 vf = swz_frag(VsL, dt * 16 + l16, ks * 4 + quad);
        oacc[dt] = __builtin_amdgcn_mfma_f32_16x16x32_bf16(pa, vf, oacc[dt], 0, 0, 0);
      }
    }
  }

  // ---- reduce lane-local sums across the 4 quads (lanes sharing l16) ----
  lsum += __shfl_xor(lsum, 16);
  lsum += __shfl_xor(lsum, 32);
  float sinv = 1.0f / lsum;   // every lane now holds 1/sum for row i = l16
  if (lane < 16)
    linv_ws[(size_t)b * NL + i0 + wave * 16 + lane] = sinv;

#pragma unroll
  for (int r = 0; r < 4; ++r) {
    float lir = __shfl(sinv, quad * 4 + r, 16);  // 1/sum for row quad*4+r
    float* crow = ctx + ((size_t)b * NL + i0 + wave * 16 + quad * 4 + r) * ND;
#pragma unroll
    for (int dt = 0; dt < 8; ++dt)
      crow[dt * 16 + l16] = oacc[dt][r] * lir;
  }
}

// ---------------- kernel B: attention = exp(QK^T)*linv ----------------
// grid (16 j-tiles, 32 i-tiles, 16 b); block 256 = 4 waves x 16 rows.
// SWAPPED mfma: lane holds 4 consecutive j for its row i=l16 -> float4 stores.
__global__ __launch_bounds__(256, 4)
void attn_probs(const float* __restrict__ q, const unsigned short* __restrict__ Kb,
                const float* __restrict__ linv_ws, float* __restrict__ attn) {
  __shared__ unsigned short KsL[128 * 128];   // linear, chunk-swizzled

  const int b    = blockIdx.z;
  const int i0   = blockIdx.y * 64;
  const int j0   = blockIdx.x * 128;
  const int tid  = threadIdx.x;
  const int wave = tid >> 6;
  const int lane = tid & 63;
  const int quad = lane >> 4;
  const int l16  = lane & 15;
  const int row0 = i0 + wave * 16;

  // issue async K staging first so HBM/L2 latency hides under Q conversion
  const unsigned short* kbb = Kb + (size_t)b * NL * ND;
#pragma unroll
  for (int r = 0; r < 8; ++r) {
    int row = wave * 4 + r * 16 + (lane >> 4);
    int c   = lane & 15;
    async_lds16(kbb + (size_t)(j0 + row) * ND + ((c ^ (row & 7)) << 3),
                KsL + (wave * 64 + r * 256) * 8);
  }

  const float* qrow = q + ((size_t)b * NL + row0 + l16) * ND;
  short8 qh[4], ql[4];
  load_q_frags(qrow, quad, qh, ql, QSCALE2);
  float li = linv_ws[(size_t)b * NL + row0 + l16];   // one linv per lane (row l16)

  __syncthreads();

#pragma unroll
  for (int jg = 0; jg < 8; ++jg) {
    f32x4 a = {0.f, 0.f, 0.f, 0.f};
#pragma unroll
    for (int kk = 0; kk < 4; ++kk) {
      short8 kf = swz_frag(KsL, jg * 16 + l16, kk * 4 + quad);
      a = __builtin_amdgcn_mfma_f32_16x16x32_bf16(kf, qh[kk], a, 0, 0, 0);
      a = __builtin_amdgcn_mfma_f32_16x16x32_bf16(kf, ql[kk], a, 0, 0, 0);
    }
    // lane holds j = jg*16 + quad*4 + r (r=0..3), row i = row0 + l16
    f32x4 o;
#pragma unroll
    for (int r = 0; r < 4; ++r) o[r] = hw_exp2(a[r]) * li;
    *(f32x4*)(attn + ((size_t)b * NL + row0 + l16) * NL + j0 + jg * 16 + quad * 4) = o;
  }
}

// ---------------- fallback: monolithic (used only if ws too small) ----------------
__global__ __launch_bounds__(256, 2)
void attn_fused(const float* __restrict__ q, const float* __restrict__ kg,
                const float* __restrict__ vg, float* __restrict__ out) {
  float* ctx  = out;
  float* attn = out + (size_t)NB * NL * ND;
  const int b    = blockIdx.y;
  const int i0   = blockIdx.x * 64;
  const int tid  = threadIdx.x;
  const int wave = tid >> 6;
  const int lane = tid & 63;
  const int quad = lane >> 4;
  const int l16  = lane & 15;

  __shared__ short Ksf[32][136];
  __shared__ short Vtf[128][40];
  __shared__ short Ps2[4][16][40];

  const float* qrow = q + ((size_t)b * NL + i0 + wave * 16 + l16) * ND;
  short8 qh[4], ql[4];
  load_q_frags(qrow, quad, qh, ql, QSCALE);

  f32x4 oacc[8];
#pragma unroll
  for (int i = 0; i < 8; ++i) oacc[i] = (f32x4){0.f, 0.f, 0.f, 0.f};
  float lsum[4] = {0.f, 0.f, 0.f, 0.f};

  const float* kb = kg + (size_t)b * NL * ND;
  const float* vb = vg + (size_t)b * NL * ND;

  for (int j0 = 0; j0 < NL; j0 += 32) {
    __syncthreads();
#pragma unroll
    for (int rr = 0; rr < 4; ++rr) {
      int idx = tid + rr * 256;
      int row = idx >> 5;
      int c4  = idx & 31;
      float4 kv = *(const float4*)(kb + (size_t)(j0 + row) * ND + c4 * 4);
      ushort4 ks;
      ks.x = bfr(kv.x); ks.y = bfr(kv.y); ks.z = bfr(kv.z); ks.w = bfr(kv.w);
      *(ushort4*)&Ksf[row][c4 * 4] = ks;
      float4 vv = *(const float4*)(vb + (size_t)(j0 + row) * ND + c4 * 4);
      Vtf[c4 * 4 + 0][row] = (short)bfr(vv.x);
      Vtf[c4 * 4 + 1][row] = (short)bfr(vv.y);
      Vtf[c4 * 4 + 2][row] = (short)bfr(vv.z);
      Vtf[c4 * 4 + 3][row] = (short)bfr(vv.w);
    }
    __syncthreads();

    f32x4 a0 = {0.f, 0.f, 0.f, 0.f}, a1 = {0.f, 0.f, 0.f, 0.f};
#pragma unroll
    for (int kk = 0; kk < 4; ++kk) {
      short8 k0 = *(const short8*)&Ksf[l16][kk * 32 + quad * 8];
      short8 k1 = *(const short8*)&Ksf[l16 + 16][kk * 32 + quad * 8];
      a0 = __builtin_amdgcn_mfma_f32_16x16x32_bf16(qh[kk], k0, a0, 0, 0, 0);
      a0 = __builtin_amdgcn_mfma_f32_16x16x32_bf16(ql[kk], k0, a0, 0, 0, 0);
      a1 = __builtin_amdgcn_mfma_f32_16x16x32_bf16(qh[kk], k1, a1, 0, 0, 0);
      a1 = __builtin_amdgcn_mfma_f32_16x16x32_bf16(ql[kk], k1, a1, 0, 0, 0);
    }
#pragma unroll
    for (int r = 0; r < 4; ++r) {
      float e0 = __expf(a0[r]);
      float e1 = __expf(a1[r]);
      lsum[r] += e0 + e1;
      Ps2[wave][quad * 4 + r][l16]      = (short)bfr(e0);
      Ps2[wave][quad * 4 + r][l16 + 16] = (short)bfr(e1);
    }
    __syncthreads();
    short8 pa = *(const short8*)&Ps2[wave][l16][quad * 8];
#pragma unroll
    for (int dt = 0; dt < 8; ++dt) {
      short8 vf = *(const short8*)&Vtf[dt * 16 + l16][quad * 8];
      oacc[dt] = __builtin_amdgcn_mfma_f32_16x16x32_bf16(pa, vf, oacc[dt], 0, 0, 0);
    }
  }

  float linv[4];
#pragma unroll
  for (int r = 0; r < 4; ++r) {
    float s = lsum[r];
    s += __shfl_xor(s, 1, 16);
    s += __shfl_xor(s, 2, 16);
    s += __shfl_xor(s, 4, 16);
    s += __shfl_xor(s, 8, 16);
    linv[r] = 1.0f / s;
  }
#pragma unroll
  for (int r = 0; r < 4; ++r) {
    float* crow = ctx + ((size_t)b * NL + i0 + wave * 16 + quad * 4 + r) * ND;
#pragma unroll
    for (int dt = 0; dt < 8; ++dt)
      crow[dt * 16 + l16] = oacc[dt][r] * linv[r];
  }

  for (int j0 = 0; j0 < NL; j0 += 32) {
    __syncthreads();
#pragma unroll
    for (int rr = 0; rr < 4; ++rr) {
      int idx = tid + rr * 256;
      int row = idx >> 5;
      int c4  = idx & 31;
      float4 kv = *(const float4*)(kb + (size_t)(j0 + row) * ND + c4 * 4);
      ushort4 ks;
      ks.x = bfr(kv.x); ks.y = bfr(kv.y); ks.z = bfr(kv.z); ks.w = bfr(kv.w);
      *(ushort4*)&Ksf[row][c4 * 4] = ks;
    }
    __syncthreads();
    f32x4 a0 = {0.f, 0.f, 0.f, 0.f}, a1 = {0.f, 0.f, 0.f, 0.f};
#pragma unroll
    for (int kk = 0; kk < 4; ++kk) {
      short8 k0 = *(const short8*)&Ksf[l16][kk * 32 + quad * 8];
      short8 k1 = *(const short8*)&Ksf[l16 + 16][kk * 32 + quad * 8];
      a0 = __builtin_amdgcn_mfma_f32_16x16x32_bf16(qh[kk], k0, a0, 0, 0, 0);
      a0 = __builtin_amdgcn_mfma_f32_16x16x32_bf16(ql[kk], k0, a0, 0, 0, 0);
      a1 = __builtin_amdgcn_mfma_f32_16x16x32_bf16(qh[kk], k1, a1, 0, 0, 0);
      a1 = __builtin_amdgcn_mfma_f32_16x16x32_bf16(ql[kk], k1, a1, 0, 0, 0);
    }
    float* arow = attn + ((size_t)b * NL + i0 + wave * 16 + quad * 4) * NL + j0;
#pragma unroll
    for (int r = 0; r < 4; ++r) {
      arow[(size_t)r * NL + l16]      = __expf(a0[r]) * linv[r];
      arow[(size_t)r * NL + l16 + 16] = __expf(a1[r]) * linv[r];
    }
  }
}

extern "C" void kernel_launch(void* const* d_in, const int* in_sizes, int n_in,
                              void* d_out, int out_size, void* d_ws, size_t ws_size,
                              hipStream_t stream) {
  const float* q = (const float*)d_in[0];
  const float* k = (const float*)d_in[1];
  const float* v = (const float*)d_in[2];
  float* out = (float*)d_out;

  if (ws_size >= (size_t)WS_NEED) {
    unsigned short* Kb = (unsigned short*)((char*)d_ws + WS_KB);
    unsigned short* Vt = (unsigned short*)((char*)d_ws + WS_VT);
    float* linv        = (float*)((char*)d_ws + WS_LINV);
    float* ctx  = out;
    float* attn = out + (size_t)NB * NL * ND;

    prep_k<<<dim3(4096), dim3(256), 0, stream>>>(k, Kb);
    prep_vt<<<dim3(64, 16), dim3(256), 0, stream>>>(v, Vt);
    attn_ctx<<<dim3(32, 16), dim3(256), 0, stream>>>(q, Kb, Vt, ctx, linv);
    attn_probs<<<dim3(16, 32, 16), dim3(256), 0, stream>>>(q, Kb, linv, attn);
  } else {
    dim3 grid(NL / 64, NB);
    attn_fused<<<grid, dim3(256), 0, stream>>>(q, k, v, out);
  }
}